// Round 2
// baseline (192.411 us; speedup 1.0000x reference)
//
#include <hip/hip_runtime.h>

#define N_NODES 8000
#define E_EDGES 128000
#define DIM 64
#define NUM_BASES 50
#define R2 400
#define CPR 4      // chunks (blocks) per relation in edge kernel
#define RT 16      // relation tile in k_relw

static __device__ __forceinline__ float bcast(float v, int lane) {
    return __uint_as_float(__builtin_amdgcn_readlane(__float_as_uint(v), lane));
}

// ---------------------------------------------------------------------------
// k_relw (tiled): rel_weight[r,i,o] = sum_b w_comp[r,b] * weight[b,i,o]
// grid = (R2/RT) * 4 position-blocks; each thread owns one float4 position
// and accumulates RT relations. weight is read only (R2/RT)=25 times total.
// ---------------------------------------------------------------------------
__global__ __launch_bounds__(256) void k_relw(const float* __restrict__ w_comp,
                                              const float* __restrict__ weight,
                                              float* __restrict__ relW) {
    const int rt = blockIdx.x >> 2;          // relation tile
    const int pb = blockIdx.x & 3;           // position block
    const int r0 = rt * RT;
    const int p = pb * 256 + threadIdx.x;    // float4 index in [0,1024)
    const float4* w4 = (const float4*)weight;
    float4 acc[RT];
#pragma unroll
    for (int rr = 0; rr < RT; ++rr) acc[rr] = make_float4(0.f, 0.f, 0.f, 0.f);
    for (int b = 0; b < NUM_BASES; ++b) {
        const float4 w = w4[b * 1024 + p];
#pragma unroll
        for (int rr = 0; rr < RT; ++rr) {
            const float c = w_comp[(r0 + rr) * NUM_BASES + b];  // uniform -> s_load
            acc[rr].x = fmaf(c, w.x, acc[rr].x);
            acc[rr].y = fmaf(c, w.y, acc[rr].y);
            acc[rr].z = fmaf(c, w.z, acc[rr].z);
            acc[rr].w = fmaf(c, w.w, acc[rr].w);
        }
    }
    float4* out4 = (float4*)relW;
#pragma unroll
    for (int rr = 0; rr < RT; ++rr) out4[(r0 + rr) * 1024 + p] = acc[rr];
}

// ---------------------------------------------------------------------------
// k_hist: etype histogram + float in-degree of dst
// ---------------------------------------------------------------------------
__global__ __launch_bounds__(256) void k_hist(const int* __restrict__ dst,
                                              const int* __restrict__ etype,
                                              int* __restrict__ cnt,
                                              float* __restrict__ in_deg) {
    const int e = blockIdx.x * 256 + threadIdx.x;
    if (e >= E_EDGES) return;
    atomicAdd(&cnt[etype[e]], 1);
    atomicAdd(&in_deg[dst[e]], 1.0f);
}

// ---------------------------------------------------------------------------
// k_scan: exclusive prefix sum of cnt[400] -> off[401] (single block, 512 thr)
// ---------------------------------------------------------------------------
__global__ __launch_bounds__(512) void k_scan(const int* __restrict__ cnt,
                                              int* __restrict__ off) {
    __shared__ int s[512];
    const int t = threadIdx.x;
    s[t] = (t < R2) ? cnt[t] : 0;
    __syncthreads();
    for (int d = 1; d < 512; d <<= 1) {
        const int v = (t >= d) ? s[t - d] : 0;
        __syncthreads();
        s[t] += v;
        __syncthreads();
    }
    if (t == 0) off[0] = 0;
    if (t < R2) off[t + 1] = s[t];
}

// ---------------------------------------------------------------------------
// k_scatter: stable-ish counting-sort scatter of (src,dst) by etype
// ---------------------------------------------------------------------------
__global__ __launch_bounds__(256) void k_scatter(const int* __restrict__ src,
                                                 const int* __restrict__ dst,
                                                 const int* __restrict__ etype,
                                                 const int* __restrict__ off,
                                                 int* __restrict__ cursor,
                                                 int* __restrict__ ssrc,
                                                 int* __restrict__ sdst) {
    const int e = blockIdx.x * 256 + threadIdx.x;
    if (e >= E_EDGES) return;
    const int r = etype[e];
    const int pos = off[r] + atomicAdd(&cursor[r], 1);
    ssrc[pos] = src[e];
    sdst[pos] = dst[e];
}

// ---------------------------------------------------------------------------
// k_edge2: relation-binned edge message + atomic aggregate.
// block = one chunk of one relation; W[r] column held in registers (lane = o).
// ---------------------------------------------------------------------------
__global__ __launch_bounds__(256) void k_edge2(const float* __restrict__ feat,
                                               const float* __restrict__ relW,
                                               const int* __restrict__ ssrc,
                                               const int* __restrict__ sdst,
                                               const int* __restrict__ off,
                                               float* __restrict__ nei_sum) {
    const int r = blockIdx.x / CPR;
    const int chunk = blockIdx.x % CPR;
    const int lane = threadIdx.x & 63;
    const int wv = threadIdx.x >> 6;
    const int beg = off[r];
    const int cnt = off[r + 1] - beg;
    const int cbeg = beg + (cnt * chunk) / CPR;
    const int cend = beg + (cnt * (chunk + 1)) / CPR;

    const float* __restrict__ W = relW + r * 4096;
    float w[64];
#pragma unroll
    for (int i = 0; i < 64; ++i) w[i] = W[i * 64 + lane];  // L1-resident after wave 0

    for (int idx = cbeg + wv; idx < cend; idx += 4) {
        const int s = ssrc[idx];
        const int d = sdst[idx];
        const float fa = feat[s * 64 + lane];              // coalesced 256B row
        float a0 = 0.f, a1 = 0.f, a2 = 0.f, a3 = 0.f;
#pragma unroll
        for (int i = 0; i < 64; i += 4) {
            a0 = fmaf(bcast(fa, i    ), w[i    ], a0);
            a1 = fmaf(bcast(fa, i + 1), w[i + 1], a1);
            a2 = fmaf(bcast(fa, i + 2), w[i + 2], a2);
            a3 = fmaf(bcast(fa, i + 3), w[i + 3], a3);
        }
        atomicAdd(&nei_sum[d * 64 + lane], (a0 + a1) + (a2 + a3));
    }
}

// ---------------------------------------------------------------------------
// k_node: h = feat@self_loop + nei_sum/max(deg,1); repr = [feat | h]
// ---------------------------------------------------------------------------
__global__ __launch_bounds__(256) void k_node(const float* __restrict__ feat,
                                              const float* __restrict__ slw,
                                              const float* __restrict__ nei_sum,
                                              const float* __restrict__ in_deg,
                                              float* __restrict__ out) {
    __shared__ float s_w[4096];
    const int t = threadIdx.x;
#pragma unroll
    for (int k = 0; k < 16; ++k) s_w[k * 256 + t] = slw[k * 256 + t];
    __syncthreads();
    const int lane = t & 63;
    const int wid = t >> 6;
    const int n = blockIdx.x * 4 + wid;
    if (n >= N_NODES) return;
    const float fa = feat[n * 64 + lane];
    float acc = 0.f;
#pragma unroll
    for (int i = 0; i < 64; ++i) {
        acc = fmaf(bcast(fa, i), s_w[i * 64 + lane], acc);  // 2-way alias: free
    }
    const float deg = in_deg[n];
    const float nm = nei_sum[n * 64 + lane] / fmaxf(deg, 1.0f);
    out[n * 128 + lane] = fa;
    out[n * 128 + 64 + lane] = acc + nm;
}

// ---------------------------------------------------------------------------
// k_rel: rel_emb_new[r,j] = sum_k rel_emb[r,k] * W_R_w[j,k] + W_R_b[j]
// ---------------------------------------------------------------------------
__global__ __launch_bounds__(256) void k_rel(const float* __restrict__ rel_emb,
                                             const float* __restrict__ Wr,
                                             const float* __restrict__ br,
                                             float* __restrict__ out) {
    __shared__ float s_wt[4096];  // s_wt[k*64+j] = Wr[j*64+k]
    const int t = threadIdx.x;
#pragma unroll
    for (int k = 0; k < 16; ++k) {
        const int idx = k * 256 + t;
        s_wt[(idx & 63) * 64 + (idx >> 6)] = Wr[idx];
    }
    __syncthreads();
    const int lane = t & 63;
    const int wid = t >> 6;
    const int r = blockIdx.x * 4 + wid;
    if (r >= R2) return;
    const float re = rel_emb[r * 64 + lane];
    float acc = br[lane];
#pragma unroll
    for (int k = 0; k < 64; ++k) {
        acc = fmaf(bcast(re, k), s_wt[k * 64 + lane], acc);
    }
    out[r * 64 + lane] = acc;
}

// ---------------------------------------------------------------------------
extern "C" void kernel_launch(void* const* d_in, const int* in_sizes, int n_in,
                              void* d_out, int out_size, void* d_ws, size_t ws_size,
                              hipStream_t stream) {
    const float* feat    = (const float*)d_in[0];   // [8000,64]
    const float* rel_emb = (const float*)d_in[1];   // [400,64]
    const float* weight  = (const float*)d_in[2];   // [50,64,64]
    const float* w_comp  = (const float*)d_in[3];   // [400,50]
    const float* slw     = (const float*)d_in[4];   // [64,64]
    const float* Wr      = (const float*)d_in[5];   // [64,64]
    const float* br      = (const float*)d_in[6];   // [64]
    const int*   src     = (const int*)d_in[7];     // [128000]
    const int*   dst     = (const int*)d_in[8];     // [128000]
    const int*   etype   = (const int*)d_in[9];     // [128000]
    float* out = (float*)d_out;

    char* ws = (char*)d_ws;
    float* relW    = (float*)(ws);                   // 6,553,600 B
    float* nei_sum = (float*)(ws + 6553600);         // 2,048,000 B
    float* in_deg  = (float*)(ws + 8601600);         //    32,000 B
    int*   cnt     = (int*)  (ws + 8633600);         //     1,600 B
    int*   cursor  = (int*)  (ws + 8635200);         //     1,600 B
    int*   off     = (int*)  (ws + 8636800);         //     1,604 B
    int*   ssrc    = (int*)  (ws + 8638464);         //   512,000 B
    int*   sdst    = (int*)  (ws + 9150464);         //   512,000 B

    // zero atomic accumulators: nei_sum + in_deg + cnt + cursor (contiguous)
    hipMemsetAsync(nei_sum, 0, 2048000 + 32000 + 1600 + 1600, stream);

    k_relw<<<(R2 / RT) * 4, 256, 0, stream>>>(w_comp, weight, relW);
    k_hist<<<E_EDGES / 256, 256, 0, stream>>>(dst, etype, cnt, in_deg);
    k_scan<<<1, 512, 0, stream>>>(cnt, off);
    k_scatter<<<E_EDGES / 256, 256, 0, stream>>>(src, dst, etype, off, cursor,
                                                 ssrc, sdst);
    k_edge2<<<R2 * CPR, 256, 0, stream>>>(feat, relW, ssrc, sdst, off, nei_sum);
    k_node<<<N_NODES / 4, 256, 0, stream>>>(feat, slw, nei_sum, in_deg, out);
    k_rel<<<R2 / 4, 256, 0, stream>>>(rel_emb, Wr, br, out + N_NODES * 128);
}

// Round 3
// 103.293 us; speedup vs baseline: 1.8628x; 1.8628x over previous
//
#include <hip/hip_runtime.h>

#define N_NODES 8000
#define E_EDGES 128000
#define NUM_BASES 50
#define R2 400
#define CPR 4      // chunks per relation in edge kernel
#define RT 16      // relation tile in relw

static __device__ __forceinline__ float bcast(float v, int lane) {
    return __uint_as_float(__builtin_amdgcn_readlane(__float_as_uint(v), lane));
}

// ---------------------------------------------------------------------------
// k_pre: blocks [0,100)   -> rel_weight = w_comp @ weight   (tiled)
//        blocks [100,600) -> etype histogram (64B-padded) + in-degree
// ---------------------------------------------------------------------------
__global__ __launch_bounds__(256) void k_pre(const float* __restrict__ w_comp,
                                             const float* __restrict__ weight,
                                             float* __restrict__ relW,
                                             const int* __restrict__ dst,
                                             const int* __restrict__ etype,
                                             int* __restrict__ cnt16,
                                             float* __restrict__ in_deg) {
    const int blk = blockIdx.x;
    const int t = threadIdx.x;
    if (blk < 100) {
        const int rt = blk >> 2;                 // relation tile [0,25)
        const int pb = blk & 3;                  // position block
        const int r0 = rt * RT;
        const int p = pb * 256 + t;              // float4 index [0,1024)
        const float4* w4 = (const float4*)weight;
        float4 acc[RT];
#pragma unroll
        for (int rr = 0; rr < RT; ++rr) acc[rr] = make_float4(0.f, 0.f, 0.f, 0.f);
        for (int b = 0; b < NUM_BASES; ++b) {
            const float4 w = w4[b * 1024 + p];
#pragma unroll
            for (int rr = 0; rr < RT; ++rr) {
                const float c = w_comp[(r0 + rr) * NUM_BASES + b];
                acc[rr].x = fmaf(c, w.x, acc[rr].x);
                acc[rr].y = fmaf(c, w.y, acc[rr].y);
                acc[rr].z = fmaf(c, w.z, acc[rr].z);
                acc[rr].w = fmaf(c, w.w, acc[rr].w);
            }
        }
        float4* out4 = (float4*)relW;
#pragma unroll
        for (int rr = 0; rr < RT; ++rr) out4[(r0 + rr) * 1024 + p] = acc[rr];
    } else {
        const int e = (blk - 100) * 256 + t;
        if (e >= E_EDGES) return;
        atomicAdd(&cnt16[etype[e] * 16], 1);     // one 64B line per counter
        atomicAdd(&in_deg[dst[e]], 1.0f);
    }
}

// ---------------------------------------------------------------------------
// k_scan: exclusive prefix sum of padded cnt -> off[401]
// ---------------------------------------------------------------------------
__global__ __launch_bounds__(512) void k_scan(const int* __restrict__ cnt16,
                                              int* __restrict__ off) {
    __shared__ int s[512];
    const int t = threadIdx.x;
    s[t] = (t < R2) ? cnt16[t * 16] : 0;
    __syncthreads();
    for (int d = 1; d < 512; d <<= 1) {
        const int v = (t >= d) ? s[t - d] : 0;
        __syncthreads();
        s[t] += v;
        __syncthreads();
    }
    if (t == 0) off[0] = 0;
    if (t < R2) off[t + 1] = s[t];
}

// ---------------------------------------------------------------------------
// k_scatter: counting-sort scatter of (src,dst) by etype (64B-padded cursor)
// ---------------------------------------------------------------------------
__global__ __launch_bounds__(256) void k_scatter(const int* __restrict__ src,
                                                 const int* __restrict__ dst,
                                                 const int* __restrict__ etype,
                                                 const int* __restrict__ off,
                                                 int* __restrict__ cursor16,
                                                 int* __restrict__ ssrc,
                                                 int* __restrict__ sdst) {
    const int e = blockIdx.x * 256 + threadIdx.x;
    if (e >= E_EDGES) return;
    const int r = etype[e];
    const int pos = off[r] + atomicAdd(&cursor16[r * 16], 1);
    ssrc[pos] = src[e];
    sdst[pos] = dst[e];
}

// ---------------------------------------------------------------------------
// k_edge2: relation-binned edge message + atomic aggregate.
// XCD-banded: blk&7 -> relation band of 50 (relW band 800KB fits 4MB L2).
// W[r] column in registers (lane = o); feat row scalarized to SGPR loads.
// ---------------------------------------------------------------------------
__global__ __launch_bounds__(256) void k_edge2(const float* __restrict__ feat,
                                               const float* __restrict__ relW,
                                               const int* __restrict__ ssrc,
                                               const int* __restrict__ sdst,
                                               const int* __restrict__ off,
                                               float* __restrict__ nei_sum) {
    const int xcd = blockIdx.x & 7;
    const int j = blockIdx.x >> 3;           // [0,200)
    const int r = xcd * 50 + (j >> 2);       // CPR=4
    const int chunk = j & 3;
    const int lane = threadIdx.x & 63;
    const int wv = threadIdx.x >> 6;
    const int beg = off[r];
    const int cnt = off[r + 1] - beg;
    const int cbeg = beg + (cnt * chunk) / CPR;
    const int cend = beg + (cnt * (chunk + 1)) / CPR;

    const float* __restrict__ W = relW + r * 4096;
    float w[64];
#pragma unroll
    for (int i = 0; i < 64; ++i) w[i] = W[i * 64 + lane];

    for (int idx = cbeg + wv; idx < cend; idx += 4) {
        const int s = __builtin_amdgcn_readfirstlane(ssrc[idx]);
        const int d = __builtin_amdgcn_readfirstlane(sdst[idx]);
        const float* __restrict__ frow = feat + s * 64;  // uniform -> s_load
        float a0 = 0.f, a1 = 0.f, a2 = 0.f, a3 = 0.f;
#pragma unroll
        for (int i = 0; i < 64; i += 4) {
            a0 = fmaf(frow[i    ], w[i    ], a0);
            a1 = fmaf(frow[i + 1], w[i + 1], a1);
            a2 = fmaf(frow[i + 2], w[i + 2], a2);
            a3 = fmaf(frow[i + 3], w[i + 3], a3);
        }
        atomicAdd(&nei_sum[d * 64 + lane], (a0 + a1) + (a2 + a3));
    }
}

// ---------------------------------------------------------------------------
// k_post: blocks [0,2000)    -> node epilogue (repr = [feat | h])
//         blocks [2000,2100) -> rel_emb @ W_R^T + b
// ---------------------------------------------------------------------------
__global__ __launch_bounds__(256) void k_post(const float* __restrict__ feat,
                                              const float* __restrict__ slw,
                                              const float* __restrict__ nei_sum,
                                              const float* __restrict__ in_deg,
                                              const float* __restrict__ rel_emb,
                                              const float* __restrict__ Wr,
                                              const float* __restrict__ br,
                                              float* __restrict__ out) {
    const int blk = blockIdx.x;
    const int t = threadIdx.x;
    const int lane = t & 63;
    const int wid = t >> 6;
    if (blk < 2000) {
        __shared__ float s_w[4096];
#pragma unroll
        for (int k = 0; k < 16; ++k) s_w[k * 256 + t] = slw[k * 256 + t];
        __syncthreads();
        const int n = blk * 4 + wid;
        const int nu = __builtin_amdgcn_readfirstlane(n);
        const float* __restrict__ frow = feat + nu * 64;   // uniform -> s_load
        const float fa = frow[lane];
        float acc = 0.f;
#pragma unroll
        for (int i = 0; i < 64; ++i) {
            acc = fmaf(frow[i], s_w[i * 64 + lane], acc);  // 2-way alias: free
        }
        const float deg = in_deg[nu];
        const float nm = nei_sum[nu * 64 + lane] / fmaxf(deg, 1.0f);
        out[nu * 128 + lane] = fa;
        out[nu * 128 + 64 + lane] = acc + nm;
    } else {
        __shared__ float s_wt[4096];  // s_wt[k*64+j] = Wr[j*64+k]
#pragma unroll
        for (int k = 0; k < 16; ++k) {
            const int idx = k * 256 + t;
            s_wt[(idx & 63) * 64 + (idx >> 6)] = Wr[idx];
        }
        __syncthreads();
        const int r = (blk - 2000) * 4 + wid;
        const float re = rel_emb[r * 64 + lane];
        float acc = br[lane];
#pragma unroll
        for (int k = 0; k < 64; ++k) {
            acc = fmaf(bcast(re, k), s_wt[k * 64 + lane], acc);
        }
        out[N_NODES * 128 + r * 64 + lane] = acc;
    }
}

// ---------------------------------------------------------------------------
extern "C" void kernel_launch(void* const* d_in, const int* in_sizes, int n_in,
                              void* d_out, int out_size, void* d_ws, size_t ws_size,
                              hipStream_t stream) {
    const float* feat    = (const float*)d_in[0];   // [8000,64]
    const float* rel_emb = (const float*)d_in[1];   // [400,64]
    const float* weight  = (const float*)d_in[2];   // [50,64,64]
    const float* w_comp  = (const float*)d_in[3];   // [400,50]
    const float* slw     = (const float*)d_in[4];   // [64,64]
    const float* Wr      = (const float*)d_in[5];   // [64,64]
    const float* br      = (const float*)d_in[6];   // [64]
    const int*   src     = (const int*)d_in[7];     // [128000]
    const int*   dst     = (const int*)d_in[8];     // [128000]
    const int*   etype   = (const int*)d_in[9];     // [128000]
    float* out = (float*)d_out;

    char* ws = (char*)d_ws;
    float* relW     = (float*)(ws);                  // 6,553,600 B
    float* nei_sum  = (float*)(ws + 6553600);        // 2,048,000 B
    float* in_deg   = (float*)(ws + 8601600);        //    32,000 B
    int*   cnt16    = (int*)  (ws + 8633600);        //    25,600 B (64B stride)
    int*   cursor16 = (int*)  (ws + 8659200);        //    25,600 B (64B stride)
    int*   off      = (int*)  (ws + 8684800);        //     1,664 B
    int*   ssrc     = (int*)  (ws + 8686464);        //   512,000 B
    int*   sdst     = (int*)  (ws + 9198464);        //   512,000 B

    // zero atomic accumulators: nei_sum + in_deg + cnt16 + cursor16 (contiguous)
    hipMemsetAsync(nei_sum, 0, 2048000 + 32000 + 25600 + 25600, stream);

    k_pre<<<600, 256, 0, stream>>>(w_comp, weight, relW, dst, etype, cnt16, in_deg);
    k_scan<<<1, 512, 0, stream>>>(cnt16, off);
    k_scatter<<<E_EDGES / 256, 256, 0, stream>>>(src, dst, etype, off, cursor16,
                                                 ssrc, sdst);
    k_edge2<<<R2 * CPR, 256, 0, stream>>>(feat, relW, ssrc, sdst, off, nei_sum);
    k_post<<<2100, 256, 0, stream>>>(feat, slw, nei_sum, in_deg, rel_emb, Wr, br,
                                     out);
}